// Round 15
// baseline (295.102 us; speedup 1.0000x reference)
//
#include <hip/hip_runtime.h>
#include <stdint.h>

typedef unsigned int u32;
typedef unsigned long long u64;

#define B_ 8
#define N_ 100000
#define C_ 10
#define K1_ 1000
#define N2_ (C_ * K1_)
#define NBIN 4096
#define CAP 4096       // fallback / topk2 sort capacity
#define CAP_C 2048     // fast-path candidate capacity per slice
#define SEGROWS 256    // fused-NMS segment rows (fallback path)
#define MIN_CONF_F 0.05f
#define NMS_IOU_F 0.4f
#define POST_IOU_F 0.65f
#define T0_F 0.985f    // conservative fast-path threshold (count ~1500 +/- 38)

#define TOTAL_F4 (B_ * N_ * C_ / 4)  // 2,000,000 float4s
#define CBLK 512                     // compact blocks
#define LCAP 1024                    // per-block local candidate capacity

// split-NMS parameters
#define NTILE 136   // upper-triangular 64x64 tiles of the 1024x1024 pair matrix
#define NB_ 8       // build blocks per slice
#define NQUAD 40    // column-quad tasks per slice (sum over c of ceil((c+1)/4))

static __device__ __forceinline__ u32 next_pow2_ge(u32 x, u32 lo, u32 hi) {
  u32 n = lo;
  while (n < x && n < hi) n <<= 1;
  return n;
}

// triangular tile id of (rt, w), w >= rt
#define TILE_ID(rt, w) ((rt) * 16 - (((rt) * ((rt) - 1)) >> 1) + ((w) - (rt)))

// ---------------------------------------------------------------------------
// Init: zero per-slice counters + fallback flags (ws is poisoned 0xAA).
// ---------------------------------------------------------------------------
__global__ void k_init(u32* __restrict__ cnt, u32* __restrict__ flag) {
  int t = threadIdx.x;
  if (t < B_ * C_) { cnt[t] = 0; flag[t] = 0; }
}

// ---------------------------------------------------------------------------
// Fast path pass 1 (LDS-staged compaction).
// ---------------------------------------------------------------------------
__global__ __launch_bounds__(256) void k_compact(const float* __restrict__ cls,
                                                 u64* __restrict__ cand,
                                                 u32* __restrict__ cnt,
                                                 u32* __restrict__ flag) {
  __shared__ u32 lcnt[B_ * C_];
  __shared__ u32 sbase[B_ * C_];
  __shared__ u32 ltot;
  __shared__ u32 lovf;
  __shared__ u64 ekey[LCAP];
  __shared__ u32 emeta[LCAP];  // (slice<<16) | local_rank

  const int tid = threadIdx.x;
  if (tid < B_ * C_) lcnt[tid] = 0;
  if (tid == 0) { ltot = 0; lovf = 0; }
  __syncthreads();

  const u32 lo = (u32)blockIdx.x * ((TOTAL_F4 + CBLK - 1) / CBLK);
  u32 hi = lo + ((TOTAL_F4 + CBLK - 1) / CBLK);
  if (hi > TOTAL_F4) hi = TOTAL_F4;

  const float4* p4 = (const float4*)cls;
  for (u32 f = lo + tid; f < hi; f += 256) {
    float4 v = p4[f];
    u32 e = f * 4u;
    float vs[4] = {v.x, v.y, v.z, v.w};
#pragma unroll
    for (int j = 0; j < 4; ++j) {
      float s = vs[j];
      if (s >= T0_F) {
        u32 g = e + (u32)j;           // flat index into (B,N,C)
        u32 gi = g / (u32)C_;         // b*N + i
        u32 c = g - gi * (u32)C_;
        u32 bi = gi / (u32)N_;
        u32 i = gi - bi * (u32)N_;
        u32 slice = bi * (u32)C_ + c;
        u32 rank = atomicAdd(&lcnt[slice], 1u);
        u32 pos = atomicAdd(&ltot, 1u);
        if (pos < LCAP) {
          ekey[pos] = ((u64)__float_as_uint(s) << 32) | (u32)(~i);
          emeta[pos] = (slice << 16) | rank;
        } else {
          lovf = 1;
        }
      }
    }
  }
  __syncthreads();

  if (lovf) {
    if (tid < B_ * C_) flag[tid] = 1;
  }
  if (tid < B_ * C_) {
    u32 n = lcnt[tid];
    sbase[tid] = n ? atomicAdd(&cnt[tid], n) : 0u;
  }
  __syncthreads();

  u32 tot = ltot;
  if (tot > LCAP) tot = LCAP;
  for (u32 p = tid; p < tot; p += 256) {
    u32 mta = emeta[p];
    u32 slice = mta >> 16;
    u32 rank = mta & 0xFFFFu;
    u32 dst = sbase[slice] + rank;
    if (dst < CAP_C) cand[(size_t)slice * CAP_C + dst] = ekey[p];
  }
}

// ---------------------------------------------------------------------------
// Bitonic sort for 1024 threads: one exchange per thread per step.
// ---------------------------------------------------------------------------
__device__ __forceinline__ void bitonic_sort_desc(u64* buf, u32 n, int tid,
                                                  int bd) {
  for (u32 kk = 2; kk <= n; kk <<= 1) {
    for (u32 j = kk >> 1; j > 0; j >>= 1) {
      for (u32 t = tid; t < (n >> 1); t += bd) {
        u32 i = ((t & ~(j - 1)) << 1) | (t & (j - 1));
        u32 l = i | j;
        u64 a = buf[i], bb = buf[l];
        bool desc = ((i & kk) == 0);
        if (desc ? (a < bb) : (a > bb)) { buf[i] = bb; buf[l] = a; }
      }
      __syncthreads();
    }
  }
}

// ---------------------------------------------------------------------------
// Fast path pass 2: per-slice adaptive bitonic sort, emit top 1000.
// ---------------------------------------------------------------------------
__global__ __launch_bounds__(1024) void k_sel(const u64* __restrict__ cand,
                                              const u32* __restrict__ cnt,
                                              u32* __restrict__ flag,
                                              float* __restrict__ score1,
                                              int* __restrict__ idx1) {
  const int slice = blockIdx.x;
  const int tid = threadIdx.x;
  __shared__ u64 buf[CAP_C];

  u32 m = cnt[slice];
  if (flag[slice] || m < (u32)K1_ || m > (u32)CAP_C) {
    if (tid == 0) flag[slice] = 1;
    return;
  }
  const u32 n = next_pow2_ge(m, 1024u, (u32)CAP_C);

  for (u32 i = tid; i < n; i += 1024)
    buf[i] = (i < m) ? cand[(size_t)slice * CAP_C + i] : 0ull;
  __syncthreads();

  bitonic_sort_desc(buf, n, tid, 1024);

  if (tid < K1_) {
    u64 e = buf[tid];
    u32 k = (u32)(e >> 32);
    score1[slice * K1_ + tid] = __uint_as_float(k);
    idx1[slice * K1_ + tid] = (int)(~(u32)e);
  }
}

// ---------------------------------------------------------------------------
// Fallback (exact, slow) per-slice top-1000 — only runs for flagged slices.
// ---------------------------------------------------------------------------
__global__ __launch_bounds__(256) void k_topk1_fb(const float* __restrict__ cls,
                                                  const u32* __restrict__ flag,
                                                  float* __restrict__ score1,
                                                  int* __restrict__ idx1) {
  const int slice = blockIdx.x;
  if (!flag[slice]) return;
  const int b = slice / C_, c = slice % C_;
  const int tid = threadIdx.x, bd = blockDim.x;

  __shared__ u32 hist[NBIN];
  __shared__ u64 buf[CAP];
  __shared__ int sh_b1;
  __shared__ u32 sh_base, sh_T, sh_cnt;

  for (int i = tid; i < NBIN; i += bd) hist[i] = 0;
  __syncthreads();
  for (int i = tid; i < N_; i += bd) {
    float s = cls[((size_t)b * N_ + i) * C_ + c];
    if (s >= MIN_CONF_F) atomicAdd(&hist[__float_as_uint(s) >> 19], 1u);
  }
  __syncthreads();
  if (tid == 0) {
    u32 cum = 0; int b1 = -1; u32 base = 0;
    for (int bin = NBIN - 1; bin >= 0; --bin) {
      cum += hist[bin];
      if (cum >= (u32)K1_) { b1 = bin; base = cum - hist[bin]; break; }
    }
    sh_b1 = b1; sh_base = base;
    if (b1 < 0) sh_T = 0;
  }
  __syncthreads();
  const int b1 = sh_b1;

  if (b1 >= 0) {
    const u32 base = sh_base;
    for (int i = tid; i < NBIN; i += bd) hist[i] = 0;
    __syncthreads();
    for (int i = tid; i < N_; i += bd) {
      float s = cls[((size_t)b * N_ + i) * C_ + c];
      if (s >= MIN_CONF_F) {
        u32 k = __float_as_uint(s);
        if ((int)(k >> 19) == b1) atomicAdd(&hist[(k >> 7) & 0xFFFu], 1u);
      }
    }
    __syncthreads();
    if (tid == 0) {
      u32 cum = base;
      u32 T = ((u32)b1) << 19;
      for (int bin = NBIN - 1; bin >= 0; --bin) {
        cum += hist[bin];
        if (cum >= (u32)K1_) { T = (((u32)b1) << 19) | (((u32)bin) << 7); break; }
      }
      sh_T = T;
    }
    __syncthreads();
  }

  if (tid == 0) sh_cnt = 0;
  __syncthreads();
  const u32 T = sh_T;
  for (int i = tid; i < N_; i += bd) {
    float s = cls[((size_t)b * N_ + i) * C_ + c];
    if (s >= MIN_CONF_F) {
      u32 k = __float_as_uint(s);
      if (k >= T) {
        u32 pos = atomicAdd(&sh_cnt, 1u);
        if (pos < CAP) buf[pos] = ((u64)k << 32) | (u32)(~(u32)i);
      }
    }
  }
  __syncthreads();
  u32 m = sh_cnt; if (m > CAP) m = CAP;
  for (int i = tid; i < CAP; i += bd)
    if ((u32)i >= m) buf[i] = 0ull;
  __syncthreads();

  for (u32 kk = 2; kk <= CAP; kk <<= 1) {
    for (u32 j = kk >> 1; j > 0; j >>= 1) {
      for (u32 i = tid; i < CAP; i += bd) {
        u32 l = i ^ j;
        if (l > i) {
          u64 a = buf[i], bb = buf[l];
          bool desc = ((i & kk) == 0);
          if (desc ? (a < bb) : (a > bb)) { buf[i] = bb; buf[l] = a; }
        }
      }
      __syncthreads();
    }
  }

  for (int p = tid; p < K1_; p += bd) {
    u64 e = buf[p];
    u32 k = (u32)(e >> 32);
    float s; int oi;
    if (k == 0) { s = -1.0f; oi = 0; }
    else { s = __uint_as_float(k); oi = (int)(~(u32)e); }
    score1[slice * K1_ + p] = s;
    idx1[slice * K1_ + p] = oi;
  }
}

// ===========================================================================
// Split NMS: prep -> build (parallel across CUs) -> hierarchical scan.
// ===========================================================================

// Prep: per slice, gather boxes once, emit corners (float4) + areas.
__global__ __launch_bounds__(256) void k_nms_prep(const float* __restrict__ scores_all,
                                                  const int* __restrict__ origs_all,
                                                  const float* __restrict__ boxes,
                                                  int bdiv,
                                                  float4* __restrict__ cor,
                                                  float* __restrict__ areag) {
  const int slice = blockIdx.x;
  const int b = slice / bdiv;
  const float* scores = scores_all + slice * K1_;
  const int* origs = origs_all + slice * K1_;
  const float* bb = boxes + (size_t)b * N_ * 4;
  for (int p = threadIdx.x; p < 1024; p += 256) {
    float s = (p < K1_) ? scores[p] : -1.0f;
    bool v = (s >= MIN_CONF_F);
    float cx = 0.f, cy = 0.f, w = 0.f, h = 0.f;
    if (v) {
      const float4 bp = *(const float4*)(bb + (size_t)origs[p] * 4);
      cx = bp.x; cy = bp.y; w = bp.z; h = bp.w;
    }
    float y1 = cy - h * 0.5f, x1 = cx - w * 0.5f;
    float y2 = cy + h * 0.5f, x2 = cx + w * 0.5f;
    cor[(slice << 10) + p] = make_float4(y1, x1, y2, x2);
    areag[(slice << 10) + p] = (y2 - y1) * (x2 - x1);
  }
}

// Build v2: blockIdx.x = slice*NB_ + sub. Each wave takes (column, row-quad)
// tasks: up to 4 row-tiles register-held (lane = row), per j one broadcast
// b128 + one ja recompute + 4 pair tests (validated R8 fused inner loop).
// Mask tiles written coalesced to maskg[slice][tile][row0..63].
__global__ __launch_bounds__(256) void k_nms_build(const float4* __restrict__ cor,
                                                   const float* __restrict__ areag,
                                                   float thr,
                                                   u64* __restrict__ maskg) {
  __shared__ float4 box4[1024];
  __shared__ float area[1024];
  const int blk = blockIdx.x;
  const int slice = blk / NB_;
  const int sub = blk - slice * NB_;
  const int tid = threadIdx.x, wave = tid >> 6, lane = tid & 63;

  for (int p = tid; p < 1024; p += 256) {
    box4[p] = cor[(slice << 10) + p];
    area[p] = areag[(slice << 10) + p];
  }
  __syncthreads();

  const float cf = thr;
  const float cnext = __uint_as_float(__float_as_uint(cf) + 1u);
  const double M = ((double)cf + (double)cnext) * 0.5;
  const bool strict = ((__float_as_uint(cf) & 1u) == 0u);

  u64* mg = maskg + (size_t)slice * (NTILE * 64);

  // tasks ordered by (col asc, quad asc): col c has ceil((c+1)/4) quads.
  for (int t = sub * 4 + wave; t < NQUAD; t += NB_ * 4) {
    // invert task id -> (col, quad)
    int col = 0, acc = 0;
    while (t >= acc + ((col + 1 + 3) >> 2)) { acc += (col + 1 + 3) >> 2; ++col; }
    const int q = t - acc;           // quad index within column
    const int rt0 = q << 2;          // first row-tile of this quad
    int ntile = col - rt0 + 1;
    if (ntile > 4) ntile = 4;

    float4 ib[4];
    float ia[4];
#pragma unroll
    for (int r = 0; r < 4; ++r) {
      if (r < ntile) {
        const int i = ((rt0 + r) << 6) + lane;
        ib[r] = box4[i];
        ia[r] = area[i];
      }
    }
    u32 mhi[4] = {0, 0, 0, 0}, mlo[4] = {0, 0, 0, 0};
    const float4* jcol = &box4[col << 6];

    for (int j = 63; j >= 32; --j) {
      const float4 jb = jcol[j];
      const float ja = (jb.z - jb.x) * (jb.w - jb.y);
#pragma unroll
      for (int r = 0; r < 4; ++r) {
        if (r < ntile) {
          float ih = fminf(ib[r].z, jb.z) - fmaxf(ib[r].x, jb.x);
          ih = fmaxf(ih, 0.0f);
          float iw_ = fminf(ib[r].w, jb.w) - fmaxf(ib[r].y, jb.y);
          iw_ = fmaxf(iw_, 0.0f);
          float inter = ih * iw_;
          float den = fmaxf((ia[r] + ja) - inter, 1e-8f);
          bool p_ = strict ? ((double)inter > M * (double)den)
                           : ((double)inter >= M * (double)den);
          mhi[r] = (mhi[r] << 1) | (p_ ? 1u : 0u);
        }
      }
    }
    for (int j = 31; j >= 0; --j) {
      const float4 jb = jcol[j];
      const float ja = (jb.z - jb.x) * (jb.w - jb.y);
#pragma unroll
      for (int r = 0; r < 4; ++r) {
        if (r < ntile) {
          float ih = fminf(ib[r].z, jb.z) - fmaxf(ib[r].x, jb.x);
          ih = fmaxf(ih, 0.0f);
          float iw_ = fminf(ib[r].w, jb.w) - fmaxf(ib[r].y, jb.y);
          iw_ = fmaxf(iw_, 0.0f);
          float inter = ih * iw_;
          float den = fmaxf((ia[r] + ja) - inter, 1e-8f);
          bool p_ = strict ? ((double)inter > M * (double)den)
                           : ((double)inter >= M * (double)den);
          mlo[r] = (mlo[r] << 1) | (p_ ? 1u : 0u);
        }
      }
    }
#pragma unroll
    for (int r = 0; r < 4; ++r) {
      if (r < ntile) {
        u64 m = ((u64)mhi[r] << 32) | (u64)mlo[r];
        if (rt0 + r == col)  // diagonal tile: keep only bits j > i (bit > lane)
          m &= (lane == 63) ? 0ull : (~0ull << (lane + 1));
        mg[(TILE_ID(rt0 + r, col) << 6) + lane] = m;  // coalesced 512-B store
      }
    }
  }
}

// Hierarchical scan core (rolled, O(1) registers). Greedy visits ONLY rows
// with nonzero suppression masks (nz ballot): zero-mask rows never change
// rem, and a row still in rem when all earlier suppressors have been applied
// is kept — so final rem == greedy keep set (exact semantics, ascending
// order). Chain is SALU + v_readlane; one barrier per group.
__device__ void scan_core(const u64* __restrict__ mg,
                          const float* __restrict__ scores,
                          u64* __restrict__ keepb) {
  const int tid = threadIdx.x, wv = tid >> 6, lane = tid & 63;

  // valid bitmask for this wave's 64 rows (wave w <-> rows [64w, 64w+64))
  float s = (tid < K1_) ? scores[tid] : -1.0f;
  const u64 myvalid = __ballot(s >= MIN_CONF_F);

  u64 ext_partial = 0;

#pragma unroll 1
  for (int g = 0; g < 16; ++g) {
    u64 Tg = 0ull;
    if (g <= wv) Tg = mg[(TILE_ID(g, wv) << 6) + lane];
    const u64 nz = __ballot(Tg != 0ull);  // suppressor rows in this tile
    if (wv == g) {
      // reduce deferred suppression across lanes (butterfly OR)
      u64 ext = ext_partial;
      for (int off = 1; off < 64; off <<= 1) {
        u32 lo = (u32)__shfl_xor((int)(u32)ext, off, 64);
        u32 hi = (u32)__shfl_xor((int)(u32)(ext >> 32), off, 64);
        ext |= ((u64)hi << 32) | lo;
      }
      // greedy over suppressor rows only (diagonal tile = Tg).
      const u32 tlo = (u32)Tg, thi = (u32)(Tg >> 32);
      u64 rem = myvalid & ~ext;
      u64 cand = rem & nz;
      while (cand) {
        int i = __ffsll((long long)cand) - 1;
        cand &= cand - 1;  // clear bit i
        if ((rem >> i) & 1ull) {
          u32 rlo = __builtin_amdgcn_readlane(tlo, i);
          u32 rhi = __builtin_amdgcn_readlane(thi, i);
          u64 row = ((u64)rhi << 32) | rlo;  // bits only > i (diag-masked)
          rem &= ~row;
          cand &= ~row;
        }
      }
      if (lane == 0) keepb[g] = rem;
    }
    __syncthreads();
    if (wv > g) {
      u64 kg = keepb[g];  // broadcast LDS read
      if ((kg >> lane) & 1ull) ext_partial |= Tg;
    }
  }
}

__global__ __launch_bounds__(1024) void k_nms_scan1(const u64* __restrict__ maskg,
                                                    const float* __restrict__ score1,
                                                    int* __restrict__ keep1) {
  __shared__ u64 keepb[16];
  const int slice = blockIdx.x;
  scan_core(maskg + (size_t)slice * (NTILE * 64), score1 + slice * K1_, keepb);
  __syncthreads();
  const int p = threadIdx.x;
  if (p < K1_)
    keep1[slice * K1_ + p] = (int)((keepb[p >> 6] >> (p & 63)) & 1ull);
}

__global__ __launch_bounds__(1024) void k_nms_scan2(const u64* __restrict__ maskg,
                                                    const float* __restrict__ sel_score,
                                                    const int* __restrict__ sel_cls,
                                                    const int* __restrict__ sel_orig,
                                                    const float* __restrict__ boxes,
                                                    float* __restrict__ out) {
  __shared__ u64 keepb[16];
  __shared__ short ord[K1_];
  __shared__ int lbase[17];
  __shared__ int ordc;
  const int b = blockIdx.x;
  const int tid = threadIdx.x;
  scan_core(maskg + (size_t)b * (NTILE * 64), sel_score + b * K1_, keepb);
  __syncthreads();

  if (tid == 0) {
    int acc = 0;
    for (int wdx = 0; wdx < 16; ++wdx) {
      lbase[wdx] = acc;
      acc += __popcll(keepb[wdx]);
    }
    lbase[16] = acc;
    ordc = acc;
  }
  __syncthreads();
  if (tid < 16) {
    u64 m = keepb[tid];
    int base = lbase[tid];
    while (m) {
      int bit = __ffsll((long long)m) - 1;
      ord[base++] = (short)((tid << 6) | bit);
      m &= m - 1;
    }
  }
  __syncthreads();

  for (int t = tid; t < K1_ * 6; t += 1024) out[(size_t)b * K1_ * 6 + t] = 0.0f;
  __syncthreads();

  const int cnt = ordc;
  for (int q = tid; q < cnt; q += 1024) {
    int p = ord[q];
    int oi = sel_orig[b * K1_ + p];
    const float4 bp = *(const float4*)(boxes + ((size_t)b * N_ + oi) * 4);
    float* o = out + ((size_t)b * K1_ + q) * 6;
    o[0] = bp.x; o[1] = bp.y; o[2] = bp.z; o[3] = bp.w;
    o[4] = (float)sel_cls[b * K1_ + p];
    o[5] = sel_score[b * K1_ + p];
  }
}

// ===========================================================================
// Fused NMS (fallback when ws is too small) — validated R8 code, verbatim.
// ===========================================================================
__device__ __forceinline__ void nms_run(const float* __restrict__ scores,
                                        const int* __restrict__ origs,
                                        const float* __restrict__ boxesB,
                                        float thr,
                                        float4* box4, float* area,
                                        u64* mask, u64* validw, u64* keepw) {
  const int tid = threadIdx.x;
  const int wave = tid >> 6, lane = tid & 63;

  {
    const int p = tid;
    float s = (p < K1_) ? scores[p] : -1.0f;
    bool v = (s >= MIN_CONF_F);
    float cx = 0.f, cy = 0.f, w = 0.f, h = 0.f;
    if (v) {
      const float4 bp = *(const float4*)(boxesB + (size_t)origs[p] * 4);
      cx = bp.x; cy = bp.y; w = bp.z; h = bp.w;
    }
    float y1 = cy - h * 0.5f, x1 = cx - w * 0.5f;
    float y2 = cy + h * 0.5f, x2 = cx + w * 0.5f;
    box4[p] = make_float4(y1, x1, y2, x2);
    area[p] = (y2 - y1) * (x2 - x1);
    u64 mb = __ballot(v);
    if (lane == 0) validw[wave] = mb;
  }
  __syncthreads();

  const float cf = thr;
  const float cnext = __uint_as_float(__float_as_uint(cf) + 1u);
  const double M = ((double)cf + (double)cnext) * 0.5;
  const bool strict = ((__float_as_uint(cf) & 1u) == 0u);

  const int ss = wave & 3, qq = wave >> 2;
  int col;
  if (qq == 0) col = ss;
  else if (qq == 1) col = 7 - ss;
  else if (qq == 2) col = 8 + ss;
  else col = 15 - ss;

  u64 vw = validw[tid & 15];
  u64 supp = 0;

  for (int seg = 0; seg < 4; ++seg) {
    const int ibase = seg * SEGROWS;
    const int lim = (K1_ - ibase < SEGROWS) ? (K1_ - ibase) : SEGROWS;
    const int rtg0 = ibase >> 6;
    int ntile = col - rtg0 + 1;
    if (ntile < 0) ntile = 0;
    if (ntile > 4) ntile = 4;

    if (ntile > 0) {
      float4 ib[4];
      float ia[4];
#pragma unroll
      for (int r = 0; r < 4; ++r) {
        if (r < ntile) {
          const int i = ibase + (r << 6) + lane;
          ib[r] = box4[i];
          ia[r] = area[i];
        }
      }
      u32 mhi[4] = {0, 0, 0, 0}, mlo[4] = {0, 0, 0, 0};
      const float4* jcol = &box4[col << 6];

      for (int j = 63; j >= 32; --j) {
        const float4 jb = jcol[j];
        const float ja = (jb.z - jb.x) * (jb.w - jb.y);
#pragma unroll
        for (int r = 0; r < 4; ++r) {
          if (r < ntile) {
            float ih = fminf(ib[r].z, jb.z) - fmaxf(ib[r].x, jb.x);
            ih = fmaxf(ih, 0.0f);
            float iw_ = fminf(ib[r].w, jb.w) - fmaxf(ib[r].y, jb.y);
            iw_ = fmaxf(iw_, 0.0f);
            float inter = ih * iw_;
            float den = fmaxf((ia[r] + ja) - inter, 1e-8f);
            bool p_ = strict ? ((double)inter > M * (double)den)
                             : ((double)inter >= M * (double)den);
            mhi[r] = (mhi[r] << 1) | (p_ ? 1u : 0u);
          }
        }
      }
      for (int j = 31; j >= 0; --j) {
        const float4 jb = jcol[j];
        const float ja = (jb.z - jb.x) * (jb.w - jb.y);
#pragma unroll
        for (int r = 0; r < 4; ++r) {
          if (r < ntile) {
            float ih = fminf(ib[r].z, jb.z) - fmaxf(ib[r].x, jb.x);
            ih = fmaxf(ih, 0.0f);
            float iw_ = fminf(ib[r].w, jb.w) - fmaxf(ib[r].y, jb.y);
            iw_ = fmaxf(iw_, 0.0f);
            float inter = ih * iw_;
            float den = fmaxf((ia[r] + ja) - inter, 1e-8f);
            bool p_ = strict ? ((double)inter > M * (double)den)
                             : ((double)inter >= M * (double)den);
            mlo[r] = (mlo[r] << 1) | (p_ ? 1u : 0u);
          }
        }
      }
#pragma unroll
      for (int r = 0; r < 4; ++r) {
        if (r < ntile) {
          u64 m = ((u64)mhi[r] << 32) | (u64)mlo[r];
          if (rtg0 + r == col)
            m &= (lane == 63) ? 0ull : (~0ull << (lane + 1));
          const int il = (r << 6) | lane;
          mask[il * 16 + (col ^ (il & 15))] = m;
        }
      }
    }
    __syncthreads();

    if (tid < 64) {
      const int l = tid & 15;
      u64 r0 = 0, r1 = 0, r2 = 0, r3 = 0;
      if (l >= ((ibase + 0) >> 6)) r0 = mask[0 * 16 + (l ^ 0)];
      if (l >= ((ibase + 1) >> 6)) r1 = mask[1 * 16 + (l ^ 1)];
      if (l >= ((ibase + 2) >> 6)) r2 = mask[2 * 16 + (l ^ 2)];
      if (l >= ((ibase + 3) >> 6)) r3 = mask[3 * 16 + (l ^ 3)];
      for (int il = 0; il < lim; il += 4) {
        const int i0 = ibase + il;
        const int n0 = (il + 4 < lim) ? il + 4 : il;
        const int n1 = (il + 5 < lim) ? il + 5 : il;
        const int n2 = (il + 6 < lim) ? il + 6 : il;
        const int n3 = (il + 7 < lim) ? il + 7 : il;
        u64 m0 = r0, m1 = r1, m2 = r2, m3 = r3;
        r0 = (l >= ((ibase + n0) >> 6)) ? mask[n0 * 16 + (l ^ (n0 & 15))] : 0ull;
        r1 = (l >= ((ibase + n1) >> 6)) ? mask[n1 * 16 + (l ^ (n1 & 15))] : 0ull;
        r2 = (l >= ((ibase + n2) >> 6)) ? mask[n2 * 16 + (l ^ (n2 & 15))] : 0ull;
        r3 = (l >= ((ibase + n3) >> 6)) ? mask[n3 * 16 + (l ^ (n3 & 15))] : 0ull;
        bool a;
        a = (tid == (i0 >> 6)) && (((vw & ~supp) >> (i0 & 63)) & 1ull);
        if (__any(a)) supp |= m0;
        a = (tid == ((i0 + 1) >> 6)) && (((vw & ~supp) >> ((i0 + 1) & 63)) & 1ull);
        if (__any(a)) supp |= m1;
        a = (tid == ((i0 + 2) >> 6)) && (((vw & ~supp) >> ((i0 + 2) & 63)) & 1ull);
        if (__any(a)) supp |= m2;
        a = (tid == ((i0 + 3) >> 6)) && (((vw & ~supp) >> ((i0 + 3) & 63)) & 1ull);
        if (__any(a)) supp |= m3;
      }
    }
    __syncthreads();
  }

  if (tid < 16) keepw[tid] = vw & ~supp;
}

__global__ __launch_bounds__(1024) void k_nms1(const float* __restrict__ boxes,
                                               const float* __restrict__ score1,
                                               const int* __restrict__ idx1,
                                               int* __restrict__ keep1) {
  __shared__ float4 box4[1024];
  __shared__ float area[1024];
  __shared__ u64 mask[SEGROWS * 16];
  __shared__ u64 validw[16], keepw[16];

  const int slice = blockIdx.x;
  const int b = slice / C_;
  nms_run(score1 + slice * K1_, idx1 + slice * K1_,
          boxes + (size_t)b * N_ * 4, NMS_IOU_F,
          box4, area, mask, validw, keepw);
  __syncthreads();

  const int p = threadIdx.x;
  if (p < K1_)
    keep1[slice * K1_ + p] = (int)((keepw[p >> 6] >> (p & 63)) & 1ull);
}

__global__ __launch_bounds__(1024) void k_nms2_out(const float* __restrict__ boxes,
                                                   const float* __restrict__ sel_score,
                                                   const int* __restrict__ sel_cls,
                                                   const int* __restrict__ sel_orig,
                                                   float* __restrict__ out) {
  __shared__ float4 box4[1024];
  __shared__ float area[1024];
  __shared__ u64 mask[SEGROWS * 16];
  __shared__ u64 validw[16], keepw[16];
  __shared__ short ord[K1_];
  __shared__ int lbase[17];
  __shared__ int ordc;

  const int b = blockIdx.x;
  const int tid = threadIdx.x;
  nms_run(sel_score + b * K1_, sel_orig + b * K1_,
          boxes + (size_t)b * N_ * 4, POST_IOU_F,
          box4, area, mask, validw, keepw);
  __syncthreads();

  if (tid == 0) {
    int acc = 0;
    for (int wdx = 0; wdx < 16; ++wdx) {
      lbase[wdx] = acc;
      acc += __popcll(keepw[wdx]);
    }
    lbase[16] = acc;
    ordc = acc;
  }
  __syncthreads();
  if (tid < 16) {
    u64 m = keepw[tid];
    int base = lbase[tid];
    while (m) {
      int bit = __ffsll((long long)m) - 1;
      ord[base++] = (short)((tid << 6) | bit);
      m &= m - 1;
    }
  }
  __syncthreads();

  for (int t = tid; t < K1_ * 6; t += 1024) out[(size_t)b * K1_ * 6 + t] = 0.0f;
  __syncthreads();

  const int cnt = ordc;
  for (int q = tid; q < cnt; q += 1024) {
    int p = ord[q];
    int oi = sel_orig[b * K1_ + p];
    const float4 bp = *(const float4*)(boxes + ((size_t)b * N_ + oi) * 4);
    float* o = out + ((size_t)b * K1_ + q) * 6;
    o[0] = bp.x; o[1] = bp.y; o[2] = bp.z; o[3] = bp.w;
    o[4] = (float)sel_cls[b * K1_ + p];
    o[5] = sel_score[b * K1_ + p];
  }
}

// ---------------------------------------------------------------------------
// Parallel boundary-bin select over a 4096-bin LDS histogram (1024 threads).
// ---------------------------------------------------------------------------
__device__ __forceinline__ void suffix_select(const u32* __restrict__ hist,
                                              u32* __restrict__ aux,
                                              u32 base, u32 K,
                                              int* out_bin, u32* out_next) {
  const int t = threadIdx.x;  // 1024
  u32 h0 = hist[4 * t], h1 = hist[4 * t + 1];
  u32 h2 = hist[4 * t + 2], h3 = hist[4 * t + 3];
  aux[t] = h0 + h1 + h2 + h3;
  __syncthreads();
  for (int off = 1; off < 1024; off <<= 1) {
    u32 v = aux[t] + ((t + off < 1024) ? aux[t + off] : 0u);
    __syncthreads();
    aux[t] = v;
    __syncthreads();
  }
  if (t == 0 && base + aux[0] < K) { *out_bin = -1; *out_next = base; }
  u32 up = (t < 1023) ? aux[t + 1] : 0u;
  u32 s3 = h3 + up;
  u32 s2 = h2 + s3;
  u32 s1 = h1 + s2;
  u32 s0 = h0 + s1;
  u32 c0 = base + s0, c1 = base + s1, c2 = base + s2, c3 = base + s3;
  u32 c4 = base + up;
  if (c0 >= K && c1 < K) { *out_bin = 4 * t;     *out_next = c1; }
  if (c1 >= K && c2 < K) { *out_bin = 4 * t + 1; *out_next = c2; }
  if (c2 >= K && c3 < K) { *out_bin = 4 * t + 2; *out_next = c3; }
  if (c3 >= K && c4 < K) { *out_bin = 4 * t + 3; *out_next = c4; }
  __syncthreads();
}

// ---------------------------------------------------------------------------
// Kernel 3: per-batch top-1000 over the C*K1 survivors (stable, flat-index
// tie-break). Parallel histogram select + 1024-thread adaptive bitonic.
// ---------------------------------------------------------------------------
__global__ __launch_bounds__(1024) void k_topk2(const float* __restrict__ score1,
                                                const int* __restrict__ idx1,
                                                const int* __restrict__ keep1,
                                                float* __restrict__ sel_score,
                                                int* __restrict__ sel_cls,
                                                int* __restrict__ sel_orig) {
  const int b = blockIdx.x;
  const int tid = threadIdx.x;

  __shared__ u32 hist[NBIN];
  __shared__ u32 aux[1024];
  __shared__ u64 buf[CAP];
  __shared__ int sh_bin;
  __shared__ u32 sh_next;
  __shared__ u32 sh_T, sh_cnt;

  for (int i = tid; i < NBIN; i += 1024) hist[i] = 0;
  __syncthreads();
  for (int f = tid; f < N2_; f += 1024) {
    if (keep1[b * N2_ + f])
      atomicAdd(&hist[__float_as_uint(score1[b * N2_ + f]) >> 19], 1u);
  }
  __syncthreads();
  suffix_select(hist, aux, 0u, (u32)K1_, &sh_bin, &sh_next);
  const int b1 = sh_bin;
  const u32 base = sh_next;

  if (b1 >= 0) {
    for (int i = tid; i < NBIN; i += 1024) hist[i] = 0;
    if (tid == 0) sh_bin = -2;
    __syncthreads();
    for (int f = tid; f < N2_; f += 1024) {
      if (keep1[b * N2_ + f]) {
        u32 k = __float_as_uint(score1[b * N2_ + f]);
        if ((int)(k >> 19) == b1) atomicAdd(&hist[(k >> 7) & 0xFFFu], 1u);
      }
    }
    __syncthreads();
    suffix_select(hist, aux, base, (u32)K1_, &sh_bin, &sh_next);
    if (tid == 0) {
      int b2 = sh_bin;
      sh_T = (b2 >= 0) ? ((((u32)b1) << 19) | (((u32)b2) << 7))
                       : (((u32)b1) << 19);
    }
  } else {
    if (tid == 0) sh_T = 0;
  }
  if (tid == 0) sh_cnt = 0;
  __syncthreads();

  const u32 T = sh_T;
  for (int f = tid; f < N2_; f += 1024) {
    if (keep1[b * N2_ + f]) {
      u32 k = __float_as_uint(score1[b * N2_ + f]);
      if (k >= T) {
        u32 pos = atomicAdd(&sh_cnt, 1u);
        if (pos < CAP) buf[pos] = ((u64)k << 32) | (u32)(~(u32)f);
      }
    }
  }
  __syncthreads();
  u32 m = sh_cnt; if (m > CAP) m = CAP;
  const u32 n = next_pow2_ge(m, 1024u, (u32)CAP);
  for (u32 i = tid; i < n; i += 1024)
    if (i >= m) buf[i] = 0ull;
  __syncthreads();

  bitonic_sort_desc(buf, n, tid, 1024);

  if (tid < K1_) {
    u64 e = buf[tid];
    u32 k = (u32)(e >> 32);
    float s; int cls, orig;
    if (k == 0) { s = -1.0f; cls = 0; orig = 0; }
    else {
      s = __uint_as_float(k);
      u32 f = ~(u32)e;
      cls = (int)(f / K1_);
      int slot = (int)(f - (u32)cls * K1_);
      orig = idx1[(b * C_ + cls) * K1_ + slot];
    }
    sel_score[b * K1_ + tid] = s;
    sel_cls[b * K1_ + tid] = cls;
    sel_orig[b * K1_ + tid] = orig;
  }
}

// ---------------------------------------------------------------------------
extern "C" void kernel_launch(void* const* d_in, const int* in_sizes, int n_in,
                              void* d_out, int out_size, void* d_ws, size_t ws_size,
                              hipStream_t stream) {
  const float* cls = (const float*)d_in[0];    // (8,100000,10) f32
  const float* boxes = (const float*)d_in[1];  // (8,100000,4)  f32
  float* out = (float*)d_out;                  // (8,1000,6)    f32

  char* ws = (char*)d_ws;
  float* score1    = (float*)(ws);                     // 80000 f32
  int*   idx1      = (int*)(ws + 320000);              // 80000 i32
  int*   keep1     = (int*)(ws + 640000);              // 80000 i32
  float* sel_score = (float*)(ws + 960000);            // 8000 f32
  int*   sel_cls   = (int*)(ws + 992000);              // 8000 i32
  int*   sel_orig  = (int*)(ws + 1024000);             // 8000 i32
  u32*   cnt       = (u32*)(ws + 1056000);             // 80 u32
  u32*   flag      = (u32*)(ws + 1056320);             // 80 u32
  u64*   cand      = (u64*)(ws + 1056640);             // 80*2048 u64, ends 2367360
  // split-NMS workspace (fast path)
  u64*    mask1 = (u64*)(ws + 2367488);                // 80*8704 u64 = 5,570,560
  u64*    mask2 = (u64*)(ws + 7938048);                // 8*8704 u64  =   557,056
  float4* cor1  = (float4*)(ws + 8495104);             // 80*1024 f4  = 1,310,720
  float*  area1 = (float*)(ws + 9805824);              // 80*1024 f32 =   327,680
  float4* cor2  = (float4*)(ws + 10133504);            // 8*1024 f4   =   131,072
  float*  area2 = (float*)(ws + 10264576);             // 8*1024 f32  =    32,768
  const size_t WS_NEED = 10297344;

  hipLaunchKernelGGL(k_init, dim3(1), dim3(256), 0, stream, cnt, flag);
  hipLaunchKernelGGL(k_compact, dim3(CBLK), dim3(256), 0, stream,
                     cls, cand, cnt, flag);
  hipLaunchKernelGGL(k_sel, dim3(B_ * C_), dim3(1024), 0, stream,
                     cand, cnt, flag, score1, idx1);
  hipLaunchKernelGGL(k_topk1_fb, dim3(B_ * C_), dim3(256), 0, stream,
                     cls, flag, score1, idx1);

  if (ws_size >= WS_NEED) {
    // fast path: parallel mask build across all CUs + register-hierarchical scans
    hipLaunchKernelGGL(k_nms_prep, dim3(B_ * C_), dim3(256), 0, stream,
                       score1, idx1, boxes, C_, cor1, area1);
    hipLaunchKernelGGL(k_nms_build, dim3(B_ * C_ * NB_), dim3(256), 0, stream,
                       cor1, area1, NMS_IOU_F, mask1);
    hipLaunchKernelGGL(k_nms_scan1, dim3(B_ * C_), dim3(1024), 0, stream,
                       mask1, score1, keep1);
    hipLaunchKernelGGL(k_topk2, dim3(B_), dim3(1024), 0, stream,
                       score1, idx1, keep1, sel_score, sel_cls, sel_orig);
    hipLaunchKernelGGL(k_nms_prep, dim3(B_), dim3(256), 0, stream,
                       sel_score, sel_orig, boxes, 1, cor2, area2);
    hipLaunchKernelGGL(k_nms_build, dim3(B_ * NB_), dim3(256), 0, stream,
                       cor2, area2, POST_IOU_F, mask2);
    hipLaunchKernelGGL(k_nms_scan2, dim3(B_), dim3(1024), 0, stream,
                       mask2, sel_score, sel_cls, sel_orig, boxes, out);
  } else {
    // fallback: fused per-slice NMS (validated R8 path)
    hipLaunchKernelGGL(k_nms1, dim3(B_ * C_), dim3(1024), 0, stream,
                       boxes, score1, idx1, keep1);
    hipLaunchKernelGGL(k_topk2, dim3(B_), dim3(1024), 0, stream,
                       score1, idx1, keep1, sel_score, sel_cls, sel_orig);
    hipLaunchKernelGGL(k_nms2_out, dim3(B_), dim3(1024), 0, stream,
                       boxes, sel_score, sel_cls, sel_orig, out);
  }
}

// Round 16
// 235.782 us; speedup vs baseline: 1.2516x; 1.2516x over previous
//
#include <hip/hip_runtime.h>
#include <stdint.h>

typedef unsigned int u32;
typedef unsigned long long u64;

#define B_ 8
#define N_ 100000
#define C_ 10
#define K1_ 1000
#define N2_ (C_ * K1_)
#define NBIN 4096
#define CAP 4096       // fallback / topk2 sort capacity
#define CAP_C 2048     // fast-path candidate capacity per slice
#define SEGROWS 256    // fused-NMS segment rows (fallback path)
#define MIN_CONF_F 0.05f
#define NMS_IOU_F 0.4f
#define POST_IOU_F 0.65f
#define T0_F 0.985f    // conservative fast-path threshold (count ~1500 +/- 38)

#define TOTAL_F4 (B_ * N_ * C_ / 4)  // 2,000,000 float4s
#define CBLK 512                     // compact blocks
#define LCAP 1024                    // per-block local candidate capacity

// split-NMS parameters
#define NTILE 136   // upper-triangular 64x64 tiles of the 1024x1024 pair matrix
#define NB_ 34      // build blocks per slice (4 waves each -> 1 tile per wave)
#define TPB_ 4      // tiles per build block

static __device__ __forceinline__ u32 next_pow2_ge(u32 x, u32 lo, u32 hi) {
  u32 n = lo;
  while (n < x && n < hi) n <<= 1;
  return n;
}

// triangular tile id of (rt, w), w >= rt
#define TILE_ID(rt, w) ((rt) * 16 - (((rt) * ((rt) - 1)) >> 1) + ((w) - (rt)))

// ---------------------------------------------------------------------------
// Init: zero per-slice counters + fallback flags (ws is poisoned 0xAA).
// ---------------------------------------------------------------------------
__global__ void k_init(u32* __restrict__ cnt, u32* __restrict__ flag) {
  int t = threadIdx.x;
  if (t < B_ * C_) { cnt[t] = 0; flag[t] = 0; }
}

// ---------------------------------------------------------------------------
// Fast path pass 1 (LDS-staged compaction).
// ---------------------------------------------------------------------------
__global__ __launch_bounds__(256) void k_compact(const float* __restrict__ cls,
                                                 u64* __restrict__ cand,
                                                 u32* __restrict__ cnt,
                                                 u32* __restrict__ flag) {
  __shared__ u32 lcnt[B_ * C_];
  __shared__ u32 sbase[B_ * C_];
  __shared__ u32 ltot;
  __shared__ u32 lovf;
  __shared__ u64 ekey[LCAP];
  __shared__ u32 emeta[LCAP];  // (slice<<16) | local_rank

  const int tid = threadIdx.x;
  if (tid < B_ * C_) lcnt[tid] = 0;
  if (tid == 0) { ltot = 0; lovf = 0; }
  __syncthreads();

  const u32 lo = (u32)blockIdx.x * ((TOTAL_F4 + CBLK - 1) / CBLK);
  u32 hi = lo + ((TOTAL_F4 + CBLK - 1) / CBLK);
  if (hi > TOTAL_F4) hi = TOTAL_F4;

  const float4* p4 = (const float4*)cls;
  for (u32 f = lo + tid; f < hi; f += 256) {
    float4 v = p4[f];
    u32 e = f * 4u;
    float vs[4] = {v.x, v.y, v.z, v.w};
#pragma unroll
    for (int j = 0; j < 4; ++j) {
      float s = vs[j];
      if (s >= T0_F) {
        u32 g = e + (u32)j;           // flat index into (B,N,C)
        u32 gi = g / (u32)C_;         // b*N + i
        u32 c = g - gi * (u32)C_;
        u32 bi = gi / (u32)N_;
        u32 i = gi - bi * (u32)N_;
        u32 slice = bi * (u32)C_ + c;
        u32 rank = atomicAdd(&lcnt[slice], 1u);
        u32 pos = atomicAdd(&ltot, 1u);
        if (pos < LCAP) {
          ekey[pos] = ((u64)__float_as_uint(s) << 32) | (u32)(~i);
          emeta[pos] = (slice << 16) | rank;
        } else {
          lovf = 1;
        }
      }
    }
  }
  __syncthreads();

  if (lovf) {
    if (tid < B_ * C_) flag[tid] = 1;
  }
  if (tid < B_ * C_) {
    u32 n = lcnt[tid];
    sbase[tid] = n ? atomicAdd(&cnt[tid], n) : 0u;
  }
  __syncthreads();

  u32 tot = ltot;
  if (tot > LCAP) tot = LCAP;
  for (u32 p = tid; p < tot; p += 256) {
    u32 mta = emeta[p];
    u32 slice = mta >> 16;
    u32 rank = mta & 0xFFFFu;
    u32 dst = sbase[slice] + rank;
    if (dst < CAP_C) cand[(size_t)slice * CAP_C + dst] = ekey[p];
  }
}

// ---------------------------------------------------------------------------
// Bitonic sort for 1024 threads: one exchange per thread per step.
// ---------------------------------------------------------------------------
__device__ __forceinline__ void bitonic_sort_desc(u64* buf, u32 n, int tid,
                                                  int bd) {
  for (u32 kk = 2; kk <= n; kk <<= 1) {
    for (u32 j = kk >> 1; j > 0; j >>= 1) {
      for (u32 t = tid; t < (n >> 1); t += bd) {
        u32 i = ((t & ~(j - 1)) << 1) | (t & (j - 1));
        u32 l = i | j;
        u64 a = buf[i], bb = buf[l];
        bool desc = ((i & kk) == 0);
        if (desc ? (a < bb) : (a > bb)) { buf[i] = bb; buf[l] = a; }
      }
      __syncthreads();
    }
  }
}

// ---------------------------------------------------------------------------
// Fast path pass 2: per-slice adaptive bitonic sort, emit top 1000.
// ---------------------------------------------------------------------------
__global__ __launch_bounds__(1024) void k_sel(const u64* __restrict__ cand,
                                              const u32* __restrict__ cnt,
                                              u32* __restrict__ flag,
                                              float* __restrict__ score1,
                                              int* __restrict__ idx1) {
  const int slice = blockIdx.x;
  const int tid = threadIdx.x;
  __shared__ u64 buf[CAP_C];

  u32 m = cnt[slice];
  if (flag[slice] || m < (u32)K1_ || m > (u32)CAP_C) {
    if (tid == 0) flag[slice] = 1;
    return;
  }
  const u32 n = next_pow2_ge(m, 1024u, (u32)CAP_C);

  for (u32 i = tid; i < n; i += 1024)
    buf[i] = (i < m) ? cand[(size_t)slice * CAP_C + i] : 0ull;
  __syncthreads();

  bitonic_sort_desc(buf, n, tid, 1024);

  if (tid < K1_) {
    u64 e = buf[tid];
    u32 k = (u32)(e >> 32);
    score1[slice * K1_ + tid] = __uint_as_float(k);
    idx1[slice * K1_ + tid] = (int)(~(u32)e);
  }
}

// ---------------------------------------------------------------------------
// Fallback (exact, slow) per-slice top-1000 — only runs for flagged slices.
// ---------------------------------------------------------------------------
__global__ __launch_bounds__(256) void k_topk1_fb(const float* __restrict__ cls,
                                                  const u32* __restrict__ flag,
                                                  float* __restrict__ score1,
                                                  int* __restrict__ idx1) {
  const int slice = blockIdx.x;
  if (!flag[slice]) return;
  const int b = slice / C_, c = slice % C_;
  const int tid = threadIdx.x, bd = blockDim.x;

  __shared__ u32 hist[NBIN];
  __shared__ u64 buf[CAP];
  __shared__ int sh_b1;
  __shared__ u32 sh_base, sh_T, sh_cnt;

  for (int i = tid; i < NBIN; i += bd) hist[i] = 0;
  __syncthreads();
  for (int i = tid; i < N_; i += bd) {
    float s = cls[((size_t)b * N_ + i) * C_ + c];
    if (s >= MIN_CONF_F) atomicAdd(&hist[__float_as_uint(s) >> 19], 1u);
  }
  __syncthreads();
  if (tid == 0) {
    u32 cum = 0; int b1 = -1; u32 base = 0;
    for (int bin = NBIN - 1; bin >= 0; --bin) {
      cum += hist[bin];
      if (cum >= (u32)K1_) { b1 = bin; base = cum - hist[bin]; break; }
    }
    sh_b1 = b1; sh_base = base;
    if (b1 < 0) sh_T = 0;
  }
  __syncthreads();
  const int b1 = sh_b1;

  if (b1 >= 0) {
    const u32 base = sh_base;
    for (int i = tid; i < NBIN; i += bd) hist[i] = 0;
    __syncthreads();
    for (int i = tid; i < N_; i += bd) {
      float s = cls[((size_t)b * N_ + i) * C_ + c];
      if (s >= MIN_CONF_F) {
        u32 k = __float_as_uint(s);
        if ((int)(k >> 19) == b1) atomicAdd(&hist[(k >> 7) & 0xFFFu], 1u);
      }
    }
    __syncthreads();
    if (tid == 0) {
      u32 cum = base;
      u32 T = ((u32)b1) << 19;
      for (int bin = NBIN - 1; bin >= 0; --bin) {
        cum += hist[bin];
        if (cum >= (u32)K1_) { T = (((u32)b1) << 19) | (((u32)bin) << 7); break; }
      }
      sh_T = T;
    }
    __syncthreads();
  }

  if (tid == 0) sh_cnt = 0;
  __syncthreads();
  const u32 T = sh_T;
  for (int i = tid; i < N_; i += bd) {
    float s = cls[((size_t)b * N_ + i) * C_ + c];
    if (s >= MIN_CONF_F) {
      u32 k = __float_as_uint(s);
      if (k >= T) {
        u32 pos = atomicAdd(&sh_cnt, 1u);
        if (pos < CAP) buf[pos] = ((u64)k << 32) | (u32)(~(u32)i);
      }
    }
  }
  __syncthreads();
  u32 m = sh_cnt; if (m > CAP) m = CAP;
  for (int i = tid; i < CAP; i += bd)
    if ((u32)i >= m) buf[i] = 0ull;
  __syncthreads();

  for (u32 kk = 2; kk <= CAP; kk <<= 1) {
    for (u32 j = kk >> 1; j > 0; j >>= 1) {
      for (u32 i = tid; i < CAP; i += bd) {
        u32 l = i ^ j;
        if (l > i) {
          u64 a = buf[i], bb = buf[l];
          bool desc = ((i & kk) == 0);
          if (desc ? (a < bb) : (a > bb)) { buf[i] = bb; buf[l] = a; }
        }
      }
      __syncthreads();
    }
  }

  for (int p = tid; p < K1_; p += bd) {
    u64 e = buf[p];
    u32 k = (u32)(e >> 32);
    float s; int oi;
    if (k == 0) { s = -1.0f; oi = 0; }
    else { s = __uint_as_float(k); oi = (int)(~(u32)e); }
    score1[slice * K1_ + p] = s;
    idx1[slice * K1_ + p] = oi;
  }
}

// ===========================================================================
// Split NMS: prep -> build (parallel across CUs) -> hierarchical scan.
// ===========================================================================

// Prep: per slice, gather boxes once, emit corners (float4) + areas.
__global__ __launch_bounds__(256) void k_nms_prep(const float* __restrict__ scores_all,
                                                  const int* __restrict__ origs_all,
                                                  const float* __restrict__ boxes,
                                                  int bdiv,
                                                  float4* __restrict__ cor,
                                                  float* __restrict__ areag) {
  const int slice = blockIdx.x;
  const int b = slice / bdiv;
  const float* scores = scores_all + slice * K1_;
  const int* origs = origs_all + slice * K1_;
  const float* bb = boxes + (size_t)b * N_ * 4;
  for (int p = threadIdx.x; p < 1024; p += 256) {
    float s = (p < K1_) ? scores[p] : -1.0f;
    bool v = (s >= MIN_CONF_F);
    float cx = 0.f, cy = 0.f, w = 0.f, h = 0.f;
    if (v) {
      const float4 bp = *(const float4*)(bb + (size_t)origs[p] * 4);
      cx = bp.x; cy = bp.y; w = bp.z; h = bp.w;
    }
    float y1 = cy - h * 0.5f, x1 = cx - w * 0.5f;
    float y2 = cy + h * 0.5f, x2 = cx + w * 0.5f;
    cor[(slice << 10) + p] = make_float4(y1, x1, y2, x2);
    areag[(slice << 10) + p] = (y2 - y1) * (x2 - x1);
  }
}

// Build (validated R14 body, one tile per wave): blockIdx.x = slice*NB_ + sub;
// each of the block's 4 waves builds one 64x64 mask tile, written coalesced
// to maskg[slice][tile][row0..63].
__global__ __launch_bounds__(256) void k_nms_build(const float4* __restrict__ cor,
                                                   const float* __restrict__ areag,
                                                   float thr,
                                                   u64* __restrict__ maskg) {
  __shared__ float4 box4[1024];
  __shared__ float area[1024];
  const int blk = blockIdx.x;
  const int slice = blk / NB_;
  const int sub = blk - slice * NB_;
  const int tid = threadIdx.x, wave = tid >> 6, lane = tid & 63;

  for (int p = tid; p < 1024; p += 256) {
    box4[p] = cor[(slice << 10) + p];
    area[p] = areag[(slice << 10) + p];
  }
  __syncthreads();

  const float cf = thr;
  const float cnext = __uint_as_float(__float_as_uint(cf) + 1u);
  const double M = ((double)cf + (double)cnext) * 0.5;
  const bool strict = ((__float_as_uint(cf) & 1u) == 0u);

  u64* mg = maskg + (size_t)slice * (NTILE * 64);

  for (int k = wave; k < TPB_; k += 4) {
    const int tt = sub * TPB_ + k;
    if (tt >= NTILE) break;
    int rt = 0, bse = 0;
    while (tt >= bse + (16 - rt)) { bse += 16 - rt; ++rt; }
    const int w = rt + (tt - bse);
    const int row = (rt << 6) | lane;

    const float4 ib = box4[row];
    const float ia = area[row];
    const float4* jcol = &box4[w << 6];
    u32 mhi = 0, mlo = 0;
#pragma unroll 8
    for (int j = 63; j >= 32; --j) {
      const float4 jb = jcol[j];
      const float ja = (jb.z - jb.x) * (jb.w - jb.y);
      float ih = fminf(ib.z, jb.z) - fmaxf(ib.x, jb.x); ih = fmaxf(ih, 0.0f);
      float iw_ = fminf(ib.w, jb.w) - fmaxf(ib.y, jb.y); iw_ = fmaxf(iw_, 0.0f);
      float inter = ih * iw_;
      float den = fmaxf((ia + ja) - inter, 1e-8f);
      bool p_ = strict ? ((double)inter > M * (double)den)
                       : ((double)inter >= M * (double)den);
      mhi = (mhi << 1) | (p_ ? 1u : 0u);
    }
#pragma unroll 8
    for (int j = 31; j >= 0; --j) {
      const float4 jb = jcol[j];
      const float ja = (jb.z - jb.x) * (jb.w - jb.y);
      float ih = fminf(ib.z, jb.z) - fmaxf(ib.x, jb.x); ih = fmaxf(ih, 0.0f);
      float iw_ = fminf(ib.w, jb.w) - fmaxf(ib.y, jb.y); iw_ = fmaxf(iw_, 0.0f);
      float inter = ih * iw_;
      float den = fmaxf((ia + ja) - inter, 1e-8f);
      bool p_ = strict ? ((double)inter > M * (double)den)
                       : ((double)inter >= M * (double)den);
      mlo = (mlo << 1) | (p_ ? 1u : 0u);
    }
    u64 m = ((u64)mhi << 32) | (u64)mlo;
    if (w == rt) m &= (lane == 63) ? 0ull : (~0ull << (lane + 1));
    mg[(tt << 6) + lane] = m;  // coalesced 512-B store
  }
}

// Hierarchical scan core (rolled, O(1) registers). Greedy visits ONLY rows
// with nonzero suppression masks (nz ballot): zero-mask rows never change
// rem, and a row still in rem when all earlier suppressors have been applied
// is kept — so final rem == greedy keep set (exact semantics, ascending
// order). Chain is SALU + v_readlane; one barrier per group.
__device__ void scan_core(const u64* __restrict__ mg,
                          const float* __restrict__ scores,
                          u64* __restrict__ keepb) {
  const int tid = threadIdx.x, wv = tid >> 6, lane = tid & 63;

  // valid bitmask for this wave's 64 rows (wave w <-> rows [64w, 64w+64))
  float s = (tid < K1_) ? scores[tid] : -1.0f;
  const u64 myvalid = __ballot(s >= MIN_CONF_F);

  u64 ext_partial = 0;

#pragma unroll 1
  for (int g = 0; g < 16; ++g) {
    u64 Tg = 0ull;
    if (g <= wv) Tg = mg[(TILE_ID(g, wv) << 6) + lane];
    const u64 nz = __ballot(Tg != 0ull);  // suppressor rows in this tile
    if (wv == g) {
      // reduce deferred suppression across lanes (butterfly OR)
      u64 ext = ext_partial;
      for (int off = 1; off < 64; off <<= 1) {
        u32 lo = (u32)__shfl_xor((int)(u32)ext, off, 64);
        u32 hi = (u32)__shfl_xor((int)(u32)(ext >> 32), off, 64);
        ext |= ((u64)hi << 32) | lo;
      }
      // greedy over suppressor rows only (diagonal tile = Tg).
      const u32 tlo = (u32)Tg, thi = (u32)(Tg >> 32);
      u64 rem = myvalid & ~ext;
      u64 cand = rem & nz;
      while (cand) {
        int i = __ffsll((long long)cand) - 1;
        cand &= cand - 1;  // clear bit i
        if ((rem >> i) & 1ull) {
          u32 rlo = __builtin_amdgcn_readlane(tlo, i);
          u32 rhi = __builtin_amdgcn_readlane(thi, i);
          u64 row = ((u64)rhi << 32) | rlo;  // bits only > i (diag-masked)
          rem &= ~row;
          cand &= ~row;
        }
      }
      if (lane == 0) keepb[g] = rem;
    }
    __syncthreads();
    if (wv > g) {
      u64 kg = keepb[g];  // broadcast LDS read
      if ((kg >> lane) & 1ull) ext_partial |= Tg;
    }
  }
}

__global__ __launch_bounds__(1024) void k_nms_scan1(const u64* __restrict__ maskg,
                                                    const float* __restrict__ score1,
                                                    int* __restrict__ keep1) {
  __shared__ u64 keepb[16];
  const int slice = blockIdx.x;
  scan_core(maskg + (size_t)slice * (NTILE * 64), score1 + slice * K1_, keepb);
  __syncthreads();
  const int p = threadIdx.x;
  if (p < K1_)
    keep1[slice * K1_ + p] = (int)((keepb[p >> 6] >> (p & 63)) & 1ull);
}

__global__ __launch_bounds__(1024) void k_nms_scan2(const u64* __restrict__ maskg,
                                                    const float* __restrict__ sel_score,
                                                    const int* __restrict__ sel_cls,
                                                    const int* __restrict__ sel_orig,
                                                    const float* __restrict__ boxes,
                                                    float* __restrict__ out) {
  __shared__ u64 keepb[16];
  __shared__ short ord[K1_];
  __shared__ int lbase[17];
  __shared__ int ordc;
  const int b = blockIdx.x;
  const int tid = threadIdx.x;
  scan_core(maskg + (size_t)b * (NTILE * 64), sel_score + b * K1_, keepb);
  __syncthreads();

  if (tid == 0) {
    int acc = 0;
    for (int wdx = 0; wdx < 16; ++wdx) {
      lbase[wdx] = acc;
      acc += __popcll(keepb[wdx]);
    }
    lbase[16] = acc;
    ordc = acc;
  }
  __syncthreads();
  if (tid < 16) {
    u64 m = keepb[tid];
    int base = lbase[tid];
    while (m) {
      int bit = __ffsll((long long)m) - 1;
      ord[base++] = (short)((tid << 6) | bit);
      m &= m - 1;
    }
  }
  __syncthreads();

  for (int t = tid; t < K1_ * 6; t += 1024) out[(size_t)b * K1_ * 6 + t] = 0.0f;
  __syncthreads();

  const int cnt = ordc;
  for (int q = tid; q < cnt; q += 1024) {
    int p = ord[q];
    int oi = sel_orig[b * K1_ + p];
    const float4 bp = *(const float4*)(boxes + ((size_t)b * N_ + oi) * 4);
    float* o = out + ((size_t)b * K1_ + q) * 6;
    o[0] = bp.x; o[1] = bp.y; o[2] = bp.z; o[3] = bp.w;
    o[4] = (float)sel_cls[b * K1_ + p];
    o[5] = sel_score[b * K1_ + p];
  }
}

// ===========================================================================
// Fused NMS (fallback when ws is too small) — validated R8 code, verbatim.
// ===========================================================================
__device__ __forceinline__ void nms_run(const float* __restrict__ scores,
                                        const int* __restrict__ origs,
                                        const float* __restrict__ boxesB,
                                        float thr,
                                        float4* box4, float* area,
                                        u64* mask, u64* validw, u64* keepw) {
  const int tid = threadIdx.x;
  const int wave = tid >> 6, lane = tid & 63;

  {
    const int p = tid;
    float s = (p < K1_) ? scores[p] : -1.0f;
    bool v = (s >= MIN_CONF_F);
    float cx = 0.f, cy = 0.f, w = 0.f, h = 0.f;
    if (v) {
      const float4 bp = *(const float4*)(boxesB + (size_t)origs[p] * 4);
      cx = bp.x; cy = bp.y; w = bp.z; h = bp.w;
    }
    float y1 = cy - h * 0.5f, x1 = cx - w * 0.5f;
    float y2 = cy + h * 0.5f, x2 = cx + w * 0.5f;
    box4[p] = make_float4(y1, x1, y2, x2);
    area[p] = (y2 - y1) * (x2 - x1);
    u64 mb = __ballot(v);
    if (lane == 0) validw[wave] = mb;
  }
  __syncthreads();

  const float cf = thr;
  const float cnext = __uint_as_float(__float_as_uint(cf) + 1u);
  const double M = ((double)cf + (double)cnext) * 0.5;
  const bool strict = ((__float_as_uint(cf) & 1u) == 0u);

  const int ss = wave & 3, qq = wave >> 2;
  int col;
  if (qq == 0) col = ss;
  else if (qq == 1) col = 7 - ss;
  else if (qq == 2) col = 8 + ss;
  else col = 15 - ss;

  u64 vw = validw[tid & 15];
  u64 supp = 0;

  for (int seg = 0; seg < 4; ++seg) {
    const int ibase = seg * SEGROWS;
    const int lim = (K1_ - ibase < SEGROWS) ? (K1_ - ibase) : SEGROWS;
    const int rtg0 = ibase >> 6;
    int ntile = col - rtg0 + 1;
    if (ntile < 0) ntile = 0;
    if (ntile > 4) ntile = 4;

    if (ntile > 0) {
      float4 ib[4];
      float ia[4];
#pragma unroll
      for (int r = 0; r < 4; ++r) {
        if (r < ntile) {
          const int i = ibase + (r << 6) + lane;
          ib[r] = box4[i];
          ia[r] = area[i];
        }
      }
      u32 mhi[4] = {0, 0, 0, 0}, mlo[4] = {0, 0, 0, 0};
      const float4* jcol = &box4[col << 6];

      for (int j = 63; j >= 32; --j) {
        const float4 jb = jcol[j];
        const float ja = (jb.z - jb.x) * (jb.w - jb.y);
#pragma unroll
        for (int r = 0; r < 4; ++r) {
          if (r < ntile) {
            float ih = fminf(ib[r].z, jb.z) - fmaxf(ib[r].x, jb.x);
            ih = fmaxf(ih, 0.0f);
            float iw_ = fminf(ib[r].w, jb.w) - fmaxf(ib[r].y, jb.y);
            iw_ = fmaxf(iw_, 0.0f);
            float inter = ih * iw_;
            float den = fmaxf((ia[r] + ja) - inter, 1e-8f);
            bool p_ = strict ? ((double)inter > M * (double)den)
                             : ((double)inter >= M * (double)den);
            mhi[r] = (mhi[r] << 1) | (p_ ? 1u : 0u);
          }
        }
      }
      for (int j = 31; j >= 0; --j) {
        const float4 jb = jcol[j];
        const float ja = (jb.z - jb.x) * (jb.w - jb.y);
#pragma unroll
        for (int r = 0; r < 4; ++r) {
          if (r < ntile) {
            float ih = fminf(ib[r].z, jb.z) - fmaxf(ib[r].x, jb.x);
            ih = fmaxf(ih, 0.0f);
            float iw_ = fminf(ib[r].w, jb.w) - fmaxf(ib[r].y, jb.y);
            iw_ = fmaxf(iw_, 0.0f);
            float inter = ih * iw_;
            float den = fmaxf((ia[r] + ja) - inter, 1e-8f);
            bool p_ = strict ? ((double)inter > M * (double)den)
                             : ((double)inter >= M * (double)den);
            mlo[r] = (mlo[r] << 1) | (p_ ? 1u : 0u);
          }
        }
      }
#pragma unroll
      for (int r = 0; r < 4; ++r) {
        if (r < ntile) {
          u64 m = ((u64)mhi[r] << 32) | (u64)mlo[r];
          if (rtg0 + r == col)
            m &= (lane == 63) ? 0ull : (~0ull << (lane + 1));
          const int il = (r << 6) | lane;
          mask[il * 16 + (col ^ (il & 15))] = m;
        }
      }
    }
    __syncthreads();

    if (tid < 64) {
      const int l = tid & 15;
      u64 r0 = 0, r1 = 0, r2 = 0, r3 = 0;
      if (l >= ((ibase + 0) >> 6)) r0 = mask[0 * 16 + (l ^ 0)];
      if (l >= ((ibase + 1) >> 6)) r1 = mask[1 * 16 + (l ^ 1)];
      if (l >= ((ibase + 2) >> 6)) r2 = mask[2 * 16 + (l ^ 2)];
      if (l >= ((ibase + 3) >> 6)) r3 = mask[3 * 16 + (l ^ 3)];
      for (int il = 0; il < lim; il += 4) {
        const int i0 = ibase + il;
        const int n0 = (il + 4 < lim) ? il + 4 : il;
        const int n1 = (il + 5 < lim) ? il + 5 : il;
        const int n2 = (il + 6 < lim) ? il + 6 : il;
        const int n3 = (il + 7 < lim) ? il + 7 : il;
        u64 m0 = r0, m1 = r1, m2 = r2, m3 = r3;
        r0 = (l >= ((ibase + n0) >> 6)) ? mask[n0 * 16 + (l ^ (n0 & 15))] : 0ull;
        r1 = (l >= ((ibase + n1) >> 6)) ? mask[n1 * 16 + (l ^ (n1 & 15))] : 0ull;
        r2 = (l >= ((ibase + n2) >> 6)) ? mask[n2 * 16 + (l ^ (n2 & 15))] : 0ull;
        r3 = (l >= ((ibase + n3) >> 6)) ? mask[n3 * 16 + (l ^ (n3 & 15))] : 0ull;
        bool a;
        a = (tid == (i0 >> 6)) && (((vw & ~supp) >> (i0 & 63)) & 1ull);
        if (__any(a)) supp |= m0;
        a = (tid == ((i0 + 1) >> 6)) && (((vw & ~supp) >> ((i0 + 1) & 63)) & 1ull);
        if (__any(a)) supp |= m1;
        a = (tid == ((i0 + 2) >> 6)) && (((vw & ~supp) >> ((i0 + 2) & 63)) & 1ull);
        if (__any(a)) supp |= m2;
        a = (tid == ((i0 + 3) >> 6)) && (((vw & ~supp) >> ((i0 + 3) & 63)) & 1ull);
        if (__any(a)) supp |= m3;
      }
    }
    __syncthreads();
  }

  if (tid < 16) keepw[tid] = vw & ~supp;
}

__global__ __launch_bounds__(1024) void k_nms1(const float* __restrict__ boxes,
                                               const float* __restrict__ score1,
                                               const int* __restrict__ idx1,
                                               int* __restrict__ keep1) {
  __shared__ float4 box4[1024];
  __shared__ float area[1024];
  __shared__ u64 mask[SEGROWS * 16];
  __shared__ u64 validw[16], keepw[16];

  const int slice = blockIdx.x;
  const int b = slice / C_;
  nms_run(score1 + slice * K1_, idx1 + slice * K1_,
          boxes + (size_t)b * N_ * 4, NMS_IOU_F,
          box4, area, mask, validw, keepw);
  __syncthreads();

  const int p = threadIdx.x;
  if (p < K1_)
    keep1[slice * K1_ + p] = (int)((keepw[p >> 6] >> (p & 63)) & 1ull);
}

__global__ __launch_bounds__(1024) void k_nms2_out(const float* __restrict__ boxes,
                                                   const float* __restrict__ sel_score,
                                                   const int* __restrict__ sel_cls,
                                                   const int* __restrict__ sel_orig,
                                                   float* __restrict__ out) {
  __shared__ float4 box4[1024];
  __shared__ float area[1024];
  __shared__ u64 mask[SEGROWS * 16];
  __shared__ u64 validw[16], keepw[16];
  __shared__ short ord[K1_];
  __shared__ int lbase[17];
  __shared__ int ordc;

  const int b = blockIdx.x;
  const int tid = threadIdx.x;
  nms_run(sel_score + b * K1_, sel_orig + b * K1_,
          boxes + (size_t)b * N_ * 4, POST_IOU_F,
          box4, area, mask, validw, keepw);
  __syncthreads();

  if (tid == 0) {
    int acc = 0;
    for (int wdx = 0; wdx < 16; ++wdx) {
      lbase[wdx] = acc;
      acc += __popcll(keepw[wdx]);
    }
    lbase[16] = acc;
    ordc = acc;
  }
  __syncthreads();
  if (tid < 16) {
    u64 m = keepw[tid];
    int base = lbase[tid];
    while (m) {
      int bit = __ffsll((long long)m) - 1;
      ord[base++] = (short)((tid << 6) | bit);
      m &= m - 1;
    }
  }
  __syncthreads();

  for (int t = tid; t < K1_ * 6; t += 1024) out[(size_t)b * K1_ * 6 + t] = 0.0f;
  __syncthreads();

  const int cnt = ordc;
  for (int q = tid; q < cnt; q += 1024) {
    int p = ord[q];
    int oi = sel_orig[b * K1_ + p];
    const float4 bp = *(const float4*)(boxes + ((size_t)b * N_ + oi) * 4);
    float* o = out + ((size_t)b * K1_ + q) * 6;
    o[0] = bp.x; o[1] = bp.y; o[2] = bp.z; o[3] = bp.w;
    o[4] = (float)sel_cls[b * K1_ + p];
    o[5] = sel_score[b * K1_ + p];
  }
}

// ---------------------------------------------------------------------------
// Parallel boundary-bin select over a 4096-bin LDS histogram (1024 threads).
// ---------------------------------------------------------------------------
__device__ __forceinline__ void suffix_select(const u32* __restrict__ hist,
                                              u32* __restrict__ aux,
                                              u32 base, u32 K,
                                              int* out_bin, u32* out_next) {
  const int t = threadIdx.x;  // 1024
  u32 h0 = hist[4 * t], h1 = hist[4 * t + 1];
  u32 h2 = hist[4 * t + 2], h3 = hist[4 * t + 3];
  aux[t] = h0 + h1 + h2 + h3;
  __syncthreads();
  for (int off = 1; off < 1024; off <<= 1) {
    u32 v = aux[t] + ((t + off < 1024) ? aux[t + off] : 0u);
    __syncthreads();
    aux[t] = v;
    __syncthreads();
  }
  if (t == 0 && base + aux[0] < K) { *out_bin = -1; *out_next = base; }
  u32 up = (t < 1023) ? aux[t + 1] : 0u;
  u32 s3 = h3 + up;
  u32 s2 = h2 + s3;
  u32 s1 = h1 + s2;
  u32 s0 = h0 + s1;
  u32 c0 = base + s0, c1 = base + s1, c2 = base + s2, c3 = base + s3;
  u32 c4 = base + up;
  if (c0 >= K && c1 < K) { *out_bin = 4 * t;     *out_next = c1; }
  if (c1 >= K && c2 < K) { *out_bin = 4 * t + 1; *out_next = c2; }
  if (c2 >= K && c3 < K) { *out_bin = 4 * t + 2; *out_next = c3; }
  if (c3 >= K && c4 < K) { *out_bin = 4 * t + 3; *out_next = c4; }
  __syncthreads();
}

// ---------------------------------------------------------------------------
// Kernel 3: per-batch top-1000 over the C*K1 survivors (stable, flat-index
// tie-break). Parallel histogram select + 1024-thread adaptive bitonic.
// ---------------------------------------------------------------------------
__global__ __launch_bounds__(1024) void k_topk2(const float* __restrict__ score1,
                                                const int* __restrict__ idx1,
                                                const int* __restrict__ keep1,
                                                float* __restrict__ sel_score,
                                                int* __restrict__ sel_cls,
                                                int* __restrict__ sel_orig) {
  const int b = blockIdx.x;
  const int tid = threadIdx.x;

  __shared__ u32 hist[NBIN];
  __shared__ u32 aux[1024];
  __shared__ u64 buf[CAP];
  __shared__ int sh_bin;
  __shared__ u32 sh_next;
  __shared__ u32 sh_T, sh_cnt;

  for (int i = tid; i < NBIN; i += 1024) hist[i] = 0;
  __syncthreads();
  for (int f = tid; f < N2_; f += 1024) {
    if (keep1[b * N2_ + f])
      atomicAdd(&hist[__float_as_uint(score1[b * N2_ + f]) >> 19], 1u);
  }
  __syncthreads();
  suffix_select(hist, aux, 0u, (u32)K1_, &sh_bin, &sh_next);
  const int b1 = sh_bin;
  const u32 base = sh_next;

  if (b1 >= 0) {
    for (int i = tid; i < NBIN; i += 1024) hist[i] = 0;
    if (tid == 0) sh_bin = -2;
    __syncthreads();
    for (int f = tid; f < N2_; f += 1024) {
      if (keep1[b * N2_ + f]) {
        u32 k = __float_as_uint(score1[b * N2_ + f]);
        if ((int)(k >> 19) == b1) atomicAdd(&hist[(k >> 7) & 0xFFFu], 1u);
      }
    }
    __syncthreads();
    suffix_select(hist, aux, base, (u32)K1_, &sh_bin, &sh_next);
    if (tid == 0) {
      int b2 = sh_bin;
      sh_T = (b2 >= 0) ? ((((u32)b1) << 19) | (((u32)b2) << 7))
                       : (((u32)b1) << 19);
    }
  } else {
    if (tid == 0) sh_T = 0;
  }
  if (tid == 0) sh_cnt = 0;
  __syncthreads();

  const u32 T = sh_T;
  for (int f = tid; f < N2_; f += 1024) {
    if (keep1[b * N2_ + f]) {
      u32 k = __float_as_uint(score1[b * N2_ + f]);
      if (k >= T) {
        u32 pos = atomicAdd(&sh_cnt, 1u);
        if (pos < CAP) buf[pos] = ((u64)k << 32) | (u32)(~(u32)f);
      }
    }
  }
  __syncthreads();
  u32 m = sh_cnt; if (m > CAP) m = CAP;
  const u32 n = next_pow2_ge(m, 1024u, (u32)CAP);
  for (u32 i = tid; i < n; i += 1024)
    if (i >= m) buf[i] = 0ull;
  __syncthreads();

  bitonic_sort_desc(buf, n, tid, 1024);

  if (tid < K1_) {
    u64 e = buf[tid];
    u32 k = (u32)(e >> 32);
    float s; int cls, orig;
    if (k == 0) { s = -1.0f; cls = 0; orig = 0; }
    else {
      s = __uint_as_float(k);
      u32 f = ~(u32)e;
      cls = (int)(f / K1_);
      int slot = (int)(f - (u32)cls * K1_);
      orig = idx1[(b * C_ + cls) * K1_ + slot];
    }
    sel_score[b * K1_ + tid] = s;
    sel_cls[b * K1_ + tid] = cls;
    sel_orig[b * K1_ + tid] = orig;
  }
}

// ---------------------------------------------------------------------------
extern "C" void kernel_launch(void* const* d_in, const int* in_sizes, int n_in,
                              void* d_out, int out_size, void* d_ws, size_t ws_size,
                              hipStream_t stream) {
  const float* cls = (const float*)d_in[0];    // (8,100000,10) f32
  const float* boxes = (const float*)d_in[1];  // (8,100000,4)  f32
  float* out = (float*)d_out;                  // (8,1000,6)    f32

  char* ws = (char*)d_ws;
  float* score1    = (float*)(ws);                     // 80000 f32
  int*   idx1      = (int*)(ws + 320000);              // 80000 i32
  int*   keep1     = (int*)(ws + 640000);              // 80000 i32
  float* sel_score = (float*)(ws + 960000);            // 8000 f32
  int*   sel_cls   = (int*)(ws + 992000);              // 8000 i32
  int*   sel_orig  = (int*)(ws + 1024000);             // 8000 i32
  u32*   cnt       = (u32*)(ws + 1056000);             // 80 u32
  u32*   flag      = (u32*)(ws + 1056320);             // 80 u32
  u64*   cand      = (u64*)(ws + 1056640);             // 80*2048 u64, ends 2367360
  // split-NMS workspace (fast path)
  u64*    mask1 = (u64*)(ws + 2367488);                // 80*8704 u64 = 5,570,560
  u64*    mask2 = (u64*)(ws + 7938048);                // 8*8704 u64  =   557,056
  float4* cor1  = (float4*)(ws + 8495104);             // 80*1024 f4  = 1,310,720
  float*  area1 = (float*)(ws + 9805824);              // 80*1024 f32 =   327,680
  float4* cor2  = (float4*)(ws + 10133504);            // 8*1024 f4   =   131,072
  float*  area2 = (float*)(ws + 10264576);             // 8*1024 f32  =    32,768
  const size_t WS_NEED = 10297344;

  hipLaunchKernelGGL(k_init, dim3(1), dim3(256), 0, stream, cnt, flag);
  hipLaunchKernelGGL(k_compact, dim3(CBLK), dim3(256), 0, stream,
                     cls, cand, cnt, flag);
  hipLaunchKernelGGL(k_sel, dim3(B_ * C_), dim3(1024), 0, stream,
                     cand, cnt, flag, score1, idx1);
  hipLaunchKernelGGL(k_topk1_fb, dim3(B_ * C_), dim3(256), 0, stream,
                     cls, flag, score1, idx1);

  if (ws_size >= WS_NEED) {
    // fast path: parallel mask build across all CUs + register-hierarchical scans
    hipLaunchKernelGGL(k_nms_prep, dim3(B_ * C_), dim3(256), 0, stream,
                       score1, idx1, boxes, C_, cor1, area1);
    hipLaunchKernelGGL(k_nms_build, dim3(B_ * C_ * NB_), dim3(256), 0, stream,
                       cor1, area1, NMS_IOU_F, mask1);
    hipLaunchKernelGGL(k_nms_scan1, dim3(B_ * C_), dim3(1024), 0, stream,
                       mask1, score1, keep1);
    hipLaunchKernelGGL(k_topk2, dim3(B_), dim3(1024), 0, stream,
                       score1, idx1, keep1, sel_score, sel_cls, sel_orig);
    hipLaunchKernelGGL(k_nms_prep, dim3(B_), dim3(256), 0, stream,
                       sel_score, sel_orig, boxes, 1, cor2, area2);
    hipLaunchKernelGGL(k_nms_build, dim3(B_ * NB_), dim3(256), 0, stream,
                       cor2, area2, POST_IOU_F, mask2);
    hipLaunchKernelGGL(k_nms_scan2, dim3(B_), dim3(1024), 0, stream,
                       mask2, sel_score, sel_cls, sel_orig, boxes, out);
  } else {
    // fallback: fused per-slice NMS (validated R8 path)
    hipLaunchKernelGGL(k_nms1, dim3(B_ * C_), dim3(1024), 0, stream,
                       boxes, score1, idx1, keep1);
    hipLaunchKernelGGL(k_topk2, dim3(B_), dim3(1024), 0, stream,
                       score1, idx1, keep1, sel_score, sel_cls, sel_orig);
    hipLaunchKernelGGL(k_nms2_out, dim3(B_), dim3(1024), 0, stream,
                       boxes, sel_score, sel_cls, sel_orig, out);
  }
}